// Round 7
// baseline (322.510 us; speedup 1.0000x reference)
//
#include <hip/hip_runtime.h>
#include <stdint.h>

// Problem constants (fixed by the reference): B=8, H=W=64, C=256
#define CC 256
#define NN 4096           // H*W
#define MM 2048           // NN/2 (pooled)
#define BB 8
#define NROWS (BB*NN)     // 32768 query rows
#define PROWS (BB*MM)     // 16384 pooled rows

typedef __attribute__((ext_vector_type(8))) short    short8;   // 8 bf16
typedef __attribute__((ext_vector_type(8))) _Float16 half8;    // 8 fp16
typedef __attribute__((ext_vector_type(4))) float    float4v;

__device__ __forceinline__ unsigned short f2bf(float f) {
    unsigned int u = __float_as_uint(f);
    u += 0x7fffu + ((u >> 16) & 1u);
    return (unsigned short)(u >> 16);
}
__device__ __forceinline__ float bf2f(unsigned short h) {
    return __uint_as_float(((unsigned int)h) << 16);
}
__device__ __forceinline__ unsigned short f2h(float f) {
    union { _Float16 h; unsigned short u; } cv; cv.h = (_Float16)f; return cv.u;
}
__device__ __forceinline__ float h2f(unsigned short u) {
    union { _Float16 h; unsigned short u; } cv; cv.u = u; return (float)cv.h;
}

// ---------------------------------------------------------------------------
// xsplit: x (fp32) -> x_hi/x_lo (bf16 split), elementwise, once.
// ---------------------------------------------------------------------------
__global__ __launch_bounds__(256) void xsplit_kernel(
    const float* __restrict__ x,
    unsigned short* __restrict__ x_hi,
    unsigned short* __restrict__ x_lo)
{
    const size_t i = ((size_t)blockIdx.x*256 + threadIdx.x) * 8;
    float4v a0 = *(const float4v*)(x + i);
    float4v a1 = *(const float4v*)(x + i + 4);
    short8 h, l;
    #pragma unroll
    for (int j = 0; j < 4; ++j) {
        unsigned short h0 = f2bf(a0[j]);
        h[j]   = (short)h0; l[j]   = (short)f2bf(a0[j] - bf2f(h0));
        unsigned short h1 = f2bf(a1[j]);
        h[4+j] = (short)h1; l[4+j] = (short)f2bf(a1[j] - bf2f(h1));
    }
    *(short8*)(x_hi + i) = h;
    *(short8*)(x_lo + i) = l;
}

// ---------------------------------------------------------------------------
// wsplit: transpose + bf16 hi/lo split the three 256x256 weights once.
// ---------------------------------------------------------------------------
__global__ void wsplit_kernel(const float* __restrict__ w_theta,
                              const float* __restrict__ w_phi,
                              const float* __restrict__ w_g,
                              unsigned short* __restrict__ wT_hi,
                              unsigned short* __restrict__ wT_lo)
{
    __shared__ float tile[64][65];
    const int widx = blockIdx.z;
    const int kt = blockIdx.x, ct = blockIdx.y;
    const float* w = (widx == 0) ? w_theta : (widx == 1) ? w_phi : w_g;
    const int t  = threadIdx.x;
    const int tc = t & 63, tr = t >> 6;
    #pragma unroll
    for (int i = 0; i < 16; ++i) {
        const int lk = tr*16 + i;
        tile[lk][tc] = w[(size_t)(kt*64 + lk)*CC + ct*64 + tc];
    }
    __syncthreads();
    #pragma unroll
    for (int i = 0; i < 16; ++i) {
        const int lc = tr*16 + i;
        float v = tile[tc][lc];
        const int c = ct*64 + lc, k = kt*64 + tc;
        unsigned short hh = f2bf(v);
        size_t o = ((size_t)widx*CC + c)*CC + k;
        wT_hi[o] = hh;
        wT_lo[o] = f2bf(v - bf2f(hh));
    }
}

// ---------------------------------------------------------------------------
// proj_kernel v6 (unchanged): one 64x64 slice of ONE projection per block.
// ---------------------------------------------------------------------------
__global__ __launch_bounds__(256, 4) void proj_kernel(
    const unsigned short* __restrict__ x_hi,
    const unsigned short* __restrict__ x_lo,
    const unsigned short* __restrict__ wT_hi,
    const unsigned short* __restrict__ wT_lo,
    unsigned short* __restrict__ th,
    unsigned short* __restrict__ ph,
    unsigned short* __restrict__ g_t)
{
    __shared__ unsigned short wt_hi[64*136];   // [64 cols][128 k + pad]
    __shared__ unsigned short wt_lo[64*136];

    const int tid  = threadIdx.x;
    const int rb   = blockIdx.x & 511;         // row-block (XCD = rb%8)
    const int cv   = blockIdx.x >> 9;          // 0..11 col-variant
    const int r0   = rb * 64;
    const int widx = cv >> 2;
    const int wc0  = (cv & 3) * 64;
    const unsigned short* wThp = wT_hi + ((size_t)widx*CC + wc0)*CC;
    const unsigned short* wTlp = wT_lo + ((size_t)widx*CC + wc0)*CC;
    const bool split3 = (widx < 2);            // theta/phi 3-pass; g 1-pass

    const int wv   = tid >> 6;
    const int lane = tid & 63;
    const int quad = lane >> 4;
    const int l15  = lane & 15;
    const int arow = r0 + wv*16 + l15;
    const unsigned short* axh = x_hi + (size_t)arow*CC + quad*8;
    const unsigned short* axl = x_lo + (size_t)arow*CC + quad*8;

    float4v acc[4];
    #pragma unroll
    for (int nf = 0; nf < 4; ++nf) acc[nf] = (float4v){0.f,0.f,0.f,0.f};

    for (int h = 0; h < 2; ++h) {
        __syncthreads();
        {   // stage pre-split W^T tile [64 cols][128 k] (pure copy)
            const int j    = tid & 63;
            const int kseg = tid >> 6;
            const size_t base = (size_t)j*CC + h*128 + kseg*32;
            const unsigned short* sh = wThp + base;
            unsigned short* dh = &wt_hi[j*136 + kseg*32];
            #pragma unroll
            for (int u = 0; u < 4; ++u)
                *(uint4*)(dh + u*8) = *(const uint4*)(sh + u*8);
            if (split3) {
                const unsigned short* sl = wTlp + base;
                unsigned short* dl = &wt_lo[j*136 + kseg*32];
                #pragma unroll
                for (int u = 0; u < 4; ++u)
                    *(uint4*)(dl + u*8) = *(const uint4*)(sl + u*8);
            }
        }
        __syncthreads();

        #pragma unroll
        for (int ks = 0; ks < 4; ++ks) {
            short8 a_hi = *(const short8*)(axh + h*128 + ks*32);
            short8 a_lo;
            if (split3) a_lo = *(const short8*)(axl + h*128 + ks*32);
            #pragma unroll
            for (int nf = 0; nf < 4; ++nf) {
                const int wrow = nf*16 + l15;
                short8 b_hi = *(const short8*)&wt_hi[wrow*136 + ks*32 + quad*8];
                acc[nf] = __builtin_amdgcn_mfma_f32_16x16x32_bf16(a_hi, b_hi, acc[nf], 0,0,0);
                if (split3) {
                    short8 b_lo = *(const short8*)&wt_lo[wrow*136 + ks*32 + quad*8];
                    acc[nf] = __builtin_amdgcn_mfma_f32_16x16x32_bf16(a_hi, b_lo, acc[nf], 0,0,0);
                    acc[nf] = __builtin_amdgcn_mfma_f32_16x16x32_bf16(a_lo, b_hi, acc[nf], 0,0,0);
                }
            }
        }
    }

    const int rowbase = r0 + wv*16 + quad*4;
    if (widx == 0) {                           // theta: unpooled, fp16 single
        #pragma unroll
        for (int nf = 0; nf < 4; ++nf) {
            const int c = wc0 + nf*16 + l15;
            #pragma unroll
            for (int r = 0; r < 4; ++r)
                th[(size_t)(rowbase + r)*CC + c] = f2h(acc[nf][r]);
        }
    } else if (widx == 1) {                    // phi: pool row pairs, fp16
        #pragma unroll
        for (int nf = 0; nf < 4; ++nf) {
            const int c = wc0 + nf*16 + l15;
            #pragma unroll
            for (int rp = 0; rp < 2; ++rp) {
                float v = fmaxf(acc[nf][2*rp], acc[nf][2*rp+1]);
                const int prow = rowbase/2 + rp;   // rowbase even -> exact
                ph[(size_t)prow*CC + c] = f2h(v);
            }
        }
    } else {                                   // g: pool, bf16, transposed
        #pragma unroll
        for (int nf = 0; nf < 4; ++nf) {
            const int c = wc0 + nf*16 + l15;
            #pragma unroll
            for (int rp = 0; rp < 2; ++rp) {
                float v = fmaxf(acc[nf][2*rp], acc[nf][2*rp+1]);
                const int prow = rowbase/2 + rp;
                const int b = prow >> 11;
                const int m = prow & 2047;
                g_t[((size_t)b*CC + c)*MM + m] = f2bf(v);
            }
        }
    }
}

// ---------------------------------------------------------------------------
// phimean: per-batch column mean of phi; 512 blocks (32 rows each).
// ---------------------------------------------------------------------------
__global__ void phimean_kernel(const unsigned short* __restrict__ ph,
                               float* __restrict__ phbar)
{
    const int b = blockIdx.x >> 6, chunk = blockIdx.x & 63;
    const int c = threadIdx.x;
    const size_t base = ((size_t)b*MM + chunk*32)*CC + c;
    float s = 0.f;
    for (int r = 0; r < 32; ++r) s += h2f(ph[base + (size_t)r*CC]);
    atomicAdd(&phbar[b*CC + c], s * (1.0f/MM));
}

// ---------------------------------------------------------------------------
// attn_kernel v11: PRODUCER/CONSUMER wave specialization.
//  Falsified so far: occupancy (R3), bank conflicts (R5), barriers+L2 (R6).
//  Remaining: S-phase LDS redundancy (4 waves x 16KB for one 16KB phi tile)
//  + burst-synchronized phases. Fix:
//   - waves 0,1 (producers): S+softmax for 2 q-subtiles each; phi B-frags
//     read once per producer (S LDS reads HALVE); 4 indep MFMA chains.
//   - waves 2,3 (consumers): PV(kt-1) from s_p[(kt-1)&1] + g (L2); each owns
//     a 128-col strip; O[4][8] accum (~128 VGPR, bounds (256,2): grid=512
//     is 2 blocks/CU anyway).
//   - S(kt) overlaps PV(kt-1) STRUCTURALLY (different waves, no reg blowup).
//   - one barrier/iter, equal count on both paths; same math & op order as
//     v6 per q-row -> absmax must stay exactly 0.0703125 (layout tripwire).
//   - keeps v10 batch<->XCD affinity (FETCH 90->33MB verified).
// ---------------------------------------------------------------------------
__global__ __launch_bounds__(256, 2) void attn_kernel(
    const float* __restrict__ x,
    const unsigned short* __restrict__ th,
    const unsigned short* __restrict__ ph,
    const unsigned short* __restrict__ g_t,
    const float* __restrict__ phbar,
    float* __restrict__ out)
{
    __shared__ unsigned short s_ph[2][32*264];   // phi dbuf fp16, padded rows
    __shared__ unsigned short s_p[2][4][16*40];  // P dbuf: [buf][qtile][16q][32k+pad]
    __shared__ float          s_l[64];           // row sums

    const int tid  = threadIdx.x;
    const int bb   = blockIdx.x & 7;           // batch == XCD (L2 affinity)
    const int qtb  = blockIdx.x >> 3;          // q-tile within batch
    const int q0   = bb*NN + qtb*64;
    const int b    = bb;
    const int wv   = tid >> 6;
    const int lane = tid & 63;
    const int quad = lane >> 4;
    const int l15  = lane & 15;

    // staging geometry (ALL threads share staging duty)
    const int sti = tid >> 3;                  // key row 0..31
    const int stc = (tid & 7) * 32;            // 32-channel segment
    const size_t phbase = (size_t)b * MM * CC;
    const unsigned short* stsrc = ph + phbase + (size_t)sti*CC + stc;

    // prologue: stage phi tile 0 into buf 0
    {
        unsigned short* dh = &s_ph[0][sti*264 + stc];
        #pragma unroll
        for (int u = 0; u < 4; ++u)
            *(uint4*)(dh + u*8) = *(const uint4*)(stsrc + u*8);
    }
    __syncthreads();

    if (wv < 2) {
        // ================= PRODUCERS (waves 0,1): S + softmax =================
        // q-subtiles 2*wv and 2*wv+1 (16 rows each)
        half8 t0[8], t1[8];
        {
            const unsigned short* bh0 = th + (size_t)(q0 + (wv*2+0)*16 + l15)*CC;
            const unsigned short* bh1 = th + (size_t)(q0 + (wv*2+1)*16 + l15)*CC;
            #pragma unroll
            for (int ks = 0; ks < 8; ++ks) {
                t0[ks] = *(const half8*)(bh0 + ks*32 + quad*8);
                t1[ks] = *(const half8*)(bh1 + ks*32 + quad*8);
            }
        }
        // per-row shifts for both q-subtiles
        float sh0[4], sh1[4];
        #pragma unroll
        for (int qt = 0; qt < 2; ++qt) {
            float sp = 0.f;
            #pragma unroll
            for (int ks = 0; ks < 8; ++ks) {
                const int k0 = ks*32 + quad*8;
                float4v m0 = *(const float4v*)&phbar[b*CC + k0];
                float4v m1 = *(const float4v*)&phbar[b*CC + k0 + 4];
                half8 tv = qt ? t1[ks] : t0[ks];
                #pragma unroll
                for (int j = 0; j < 4; ++j) {
                    sp += (float)tv[j]   * m0[j];
                    sp += (float)tv[4+j] * m1[j];
                }
            }
            sp += __shfl_xor(sp, 16);
            sp += __shfl_xor(sp, 32);
            #pragma unroll
            for (int r = 0; r < 4; ++r) {
                float v = __shfl(sp, quad*4 + r) + 128.f;
                if (qt) sh1[r] = v; else sh0[r] = v;
            }
        }

        float4v accl0 = (float4v){0.f,0.f,0.f,0.f};
        float4v accl1 = (float4v){0.f,0.f,0.f,0.f};
        short8 ones;
        #pragma unroll
        for (int j = 0; j < 8; ++j) ones[j] = (short)0x3F80;   // bf16 1.0

        for (int kt = 0; kt < 64; ++kt) {
            const int key0 = kt * 32;
            const int cur  = kt & 1;

            // next-tile phi loads (shared staging duty)
            uint4 stg[4];
            if (kt < 63) {
                const unsigned short* sn = stsrc + (size_t)(key0 + 32)*CC;
                #pragma unroll
                for (int u = 0; u < 4; ++u) stg[u] = *(const uint4*)(sn + u*8);
            }

            // S for both q-subtiles: phi frags read ONCE, 4 indep chains
            float4v S00 = (float4v){0.f,0.f,0.f,0.f};
            float4v S01 = (float4v){0.f,0.f,0.f,0.f};
            float4v S10 = (float4v){0.f,0.f,0.f,0.f};
            float4v S11 = (float4v){0.f,0.f,0.f,0.f};
            #pragma unroll
            for (int ks = 0; ks < 8; ++ks) {
                half8 b0 = *(const half8*)&s_ph[cur][( 0 + l15)*264 + ks*32 + quad*8];
                half8 b1 = *(const half8*)&s_ph[cur][(16 + l15)*264 + ks*32 + quad*8];
                S00 = __builtin_amdgcn_mfma_f32_16x16x32_f16(t0[ks], b0, S00, 0,0,0);
                S01 = __builtin_amdgcn_mfma_f32_16x16x32_f16(t0[ks], b1, S01, 0,0,0);
                S10 = __builtin_amdgcn_mfma_f32_16x16x32_f16(t1[ks], b0, S10, 0,0,0);
                S11 = __builtin_amdgcn_mfma_f32_16x16x32_f16(t1[ks], b1, S11, 0,0,0);
            }

            // softmax numerators -> bf16 into s_p[cur][2wv+qt]
            {
                unsigned short* pw0 = &s_p[cur][wv*2+0][0];
                unsigned short* pw1 = &s_p[cur][wv*2+1][0];
                #pragma unroll
                for (int r = 0; r < 4; ++r) {
                    float a0 = fminf(fmaxf(S00[r] - sh0[r], -85.f), 85.f);
                    float a1 = fminf(fmaxf(S01[r] - sh0[r], -85.f), 85.f);
                    pw0[(quad*4 + r)*40 + l15]      = f2bf(__expf(a0));
                    pw0[(quad*4 + r)*40 + 16 + l15] = f2bf(__expf(a1));
                    float a2 = fminf(fmaxf(S10[r] - sh1[r], -85.f), 85.f);
                    float a3 = fminf(fmaxf(S11[r] - sh1[r], -85.f), 85.f);
                    pw1[(quad*4 + r)*40 + l15]      = f2bf(__expf(a2));
                    pw1[(quad*4 + r)*40 + 16 + l15] = f2bf(__expf(a3));
                }
            }
            asm volatile("s_waitcnt lgkmcnt(0)" ::: "memory");
            // own-row l accumulation (own s_p regions; intra-wave wait only)
            {
                short8 p0 = *(const short8*)&s_p[cur][wv*2+0][l15*40 + quad*8];
                accl0 = __builtin_amdgcn_mfma_f32_16x16x32_bf16(p0, ones, accl0, 0,0,0);
                short8 p1 = *(const short8*)&s_p[cur][wv*2+1][l15*40 + quad*8];
                accl1 = __builtin_amdgcn_mfma_f32_16x16x32_bf16(p1, ones, accl1, 0,0,0);
            }
            // write staged phi into the other buffer
            if (kt < 63) {
                unsigned short* dh = &s_ph[cur ^ 1][sti*264 + stc];
                #pragma unroll
                for (int u = 0; u < 4; ++u) *(uint4*)(dh + u*8) = stg[u];
            }
            __syncthreads();   // P(kt)+phi(kt+1) visible; s_p[cur^1] free
        }

        // row sums -> s_l
        if (l15 == 0) {
            #pragma unroll
            for (int r = 0; r < 4; ++r) {
                s_l[(wv*2+0)*16 + quad*4 + r] = accl0[r];
                s_l[(wv*2+1)*16 + quad*4 + r] = accl1[r];
            }
        }
    } else {
        // ================= CONSUMERS (waves 2,3): PV =================
        const int cw = wv - 2;                 // col half 0/1 (128 cols)
        const unsigned short* gl =
            g_t + ((size_t)b*CC + cw*128 + l15)*MM + quad*8;

        float4v O[4][8];
        #pragma unroll
        for (int qt = 0; qt < 4; ++qt)
            #pragma unroll
            for (int ct = 0; ct < 8; ++ct) O[qt][ct] = (float4v){0.f,0.f,0.f,0.f};

        for (int kt = 0; kt < 64; ++kt) {
            const int cur = kt & 1;

            // next-tile phi loads (shared staging duty)
            uint4 stg[4];
            if (kt < 63) {
                const unsigned short* sn = stsrc + (size_t)(kt*32 + 32)*CC;
                #pragma unroll
                for (int u = 0; u < 4; ++u) stg[u] = *(const uint4*)(sn + u*8);
            }

            if (kt > 0) {
                const int key0 = (kt-1) * 32;
                const int pb   = (kt-1) & 1;
                short8 gf[8];
                #pragma unroll
                for (int ct = 0; ct < 8; ++ct)
                    gf[ct] = *(const short8*)(gl + (size_t)ct*16*MM + key0);
                #pragma unroll
                for (int qt = 0; qt < 4; ++qt) {
                    short8 pA = *(const short8*)&s_p[pb][qt][l15*40 + quad*8];
                    #pragma unroll
                    for (int ct = 0; ct < 8; ++ct)
                        O[qt][ct] = __builtin_amdgcn_mfma_f32_16x16x32_bf16(pA, gf[ct], O[qt][ct], 0,0,0);
                }
            }

            if (kt < 63) {
                unsigned short* dh = &s_ph[cur ^ 1][sti*264 + stc];
                #pragma unroll
                for (int u = 0; u < 4; ++u) *(uint4*)(dh + u*8) = stg[u];
            }
            __syncthreads();
        }

        // drain: PV(63) from s_p[1] (stable after last barrier)
        {
            const int key0 = 63 * 32;
            short8 gf[8];
            #pragma unroll
            for (int ct = 0; ct < 8; ++ct)
                gf[ct] = *(const short8*)(gl + (size_t)ct*16*MM + key0);
            #pragma unroll
            for (int qt = 0; qt < 4; ++qt) {
                short8 pA = *(const short8*)&s_p[1][qt][l15*40 + quad*8];
                #pragma unroll
                for (int ct = 0; ct < 8; ++ct)
                    O[qt][ct] = __builtin_amdgcn_mfma_f32_16x16x32_bf16(pA, gf[ct], O[qt][ct], 0,0,0);
            }
        }

        __syncthreads();   // join barrier (matches producers' join below)

        // epilogue: y = O/l, out = x + y (consumer cw owns cols cw*128..+127)
        #pragma unroll
        for (int qt = 0; qt < 4; ++qt) {
            #pragma unroll
            for (int r = 0; r < 4; ++r) {
                const int row = q0 + qt*16 + quad*4 + r;
                const float rl = 1.0f / s_l[qt*16 + quad*4 + r];
                #pragma unroll
                for (int ct = 0; ct < 8; ++ct) {
                    const int c = cw*128 + ct*16 + l15;
                    const size_t idx = (size_t)row*CC + c;
                    out[idx] = x[idx] + O[qt][ct][r] * rl;
                }
            }
        }
        return;
    }

    __syncthreads();   // producers' join barrier (consumers hit theirs above)
}

// ---------------------------------------------------------------------------
extern "C" void kernel_launch(void* const* d_in, const int* in_sizes, int n_in,
                              void* d_out, int out_size, void* d_ws, size_t ws_size,
                              hipStream_t stream) {
    const float* x       = (const float*)d_in[0];
    const float* w_theta = (const float*)d_in[1];
    const float* w_phi   = (const float*)d_in[2];
    const float* w_g     = (const float*)d_in[3];
    float* out = (float*)d_out;

    // workspace (~51.2 MB)
    unsigned short* th    = (unsigned short*)d_ws;                 // fp16 16.78 MB
    unsigned short* ph    = th    + (size_t)NROWS*CC;              // fp16  8.39 MB
    unsigned short* g_t   = ph    + (size_t)PROWS*CC;              // bf16  8.39 MB
    unsigned short* x_hi  = g_t   + (size_t)PROWS*CC;              // bf16  8.39 MB
    unsigned short* x_lo  = x_hi  + (size_t)NROWS*CC;              // bf16  8.39 MB
    unsigned short* wT_hi = x_lo  + (size_t)NROWS*CC;              // bf16  0.39 MB
    unsigned short* wT_lo = wT_hi + (size_t)3*CC*CC;               // bf16  0.39 MB
    float*          phbar = (float*)(wT_lo + (size_t)3*CC*CC);     // fp32  8 KB

    hipMemsetAsync(phbar, 0, BB*CC*sizeof(float), stream);
    xsplit_kernel<<<NROWS*CC/8/256, 256, 0, stream>>>(x, x_hi, x_lo);
    wsplit_kernel<<<dim3(4,4,3), 256, 0, stream>>>(w_theta, w_phi, w_g, wT_hi, wT_lo);
    proj_kernel<<<6144, 256, 0, stream>>>(x_hi, x_lo, wT_hi, wT_lo, th, ph, g_t);
    phimean_kernel<<<512, 256, 0, stream>>>(ph, phbar);
    attn_kernel<<<NROWS/64, 256, 0, stream>>>(x, th, ph, g_t, phbar, out);
}